// Round 1
// baseline (1726.682 us; speedup 1.0000x reference)
//
#include <hip/hip_runtime.h>
#include <hip/hip_bf16.h>

#define N_NODES  50000
#define N_EDGES  800000
#define N_GRAPHS 512
#define IN_DIM   128
#define HIDDEN   64

// ---------------------------------------------------------------------------
// degree histogram over dst (self-loop handled analytically as +1)
__global__ __launch_bounds__(256) void k_deg(const int* __restrict__ dst,
                                             float* __restrict__ deg) {
    int e = blockIdx.x * 256 + threadIdx.x;
    if (e < N_EDGES) atomicAdd(&deg[dst[e]], 1.0f);
}

__global__ __launch_bounds__(256) void k_dinv(float* __restrict__ deg) {
    int i = blockIdx.x * 256 + threadIdx.x;
    if (i < N_NODES) deg[i] = rsqrtf(deg[i] + 1.0f);  // deg incl. self-loop
}

// ---------------------------------------------------------------------------
// GEMM: out[N][64] = f(A)[N][K] @ W[K][64], f = identity or relu(x + bin)
// block = 256 threads, 16 rows per block.
template <int K, bool RELU_IN>
__global__ __launch_bounds__(256) void k_gemm64(const float* __restrict__ A,
                                                const float* __restrict__ W,
                                                const float* __restrict__ bin,
                                                float* __restrict__ out) {
    __shared__ float sW[K * 64];
    __shared__ float sA[16][K];
    const int tid = threadIdx.x;
    const int rowBase = blockIdx.x * 16;

    for (int i = tid; i < K * 64; i += 256) sW[i] = W[i];
    for (int i = tid; i < 16 * K; i += 256) {
        int r = i / K, k = i % K;
        int gr = rowBase + r;
        float v = (gr < N_NODES) ? A[gr * K + k] : 0.0f;
        if (RELU_IN) v = fmaxf(v + bin[k], 0.0f);
        sA[r][k] = v;
    }
    __syncthreads();

    const int c  = tid & 63;   // output column
    const int rb = tid >> 6;   // 0..3 row subgroup
    float acc0 = 0.f, acc1 = 0.f, acc2 = 0.f, acc3 = 0.f;
    for (int k = 0; k < K; ++k) {
        float w = sW[k * 64 + c];
        acc0 = fmaf(sA[rb + 0][k],  w, acc0);
        acc1 = fmaf(sA[rb + 4][k],  w, acc1);
        acc2 = fmaf(sA[rb + 8][k],  w, acc2);
        acc3 = fmaf(sA[rb + 12][k], w, acc3);
    }
    float acc[4] = {acc0, acc1, acc2, acc3};
    for (int j = 0; j < 4; ++j) {
        int r = rowBase + rb + j * 4;
        if (r < N_NODES) out[r * 64 + c] = acc[j];
    }
}

// out[N][2] = relu(A + b2) @ W3[64][2]
__global__ __launch_bounds__(256) void k_gemm2(const float* __restrict__ A,
                                               const float* __restrict__ W3,
                                               const float* __restrict__ b2,
                                               float* __restrict__ out) {
    __shared__ float sW[128];
    __shared__ float sB[64];
    int tid = threadIdx.x;
    if (tid < 128) sW[tid] = W3[tid];
    if (tid < 64)  sB[tid] = b2[tid];
    __syncthreads();
    int i = blockIdx.x * 256 + tid;
    if (i >= N_NODES) return;
    float a0 = 0.f, a1 = 0.f;
    const float* row = A + (size_t)i * 64;
    #pragma unroll
    for (int k = 0; k < 64; k += 4) {
        float4 v = *reinterpret_cast<const float4*>(row + k);
        float z;
        z = fmaxf(v.x + sB[k + 0], 0.f); a0 = fmaf(z, sW[(k+0)*2+0], a0); a1 = fmaf(z, sW[(k+0)*2+1], a1);
        z = fmaxf(v.y + sB[k + 1], 0.f); a0 = fmaf(z, sW[(k+1)*2+0], a0); a1 = fmaf(z, sW[(k+1)*2+1], a1);
        z = fmaxf(v.z + sB[k + 2], 0.f); a0 = fmaf(z, sW[(k+2)*2+0], a0); a1 = fmaf(z, sW[(k+2)*2+1], a1);
        z = fmaxf(v.w + sB[k + 3], 0.f); a0 = fmaf(z, sW[(k+3)*2+0], a0); a1 = fmaf(z, sW[(k+3)*2+1], a1);
    }
    out[i * 2 + 0] = a0;
    out[i * 2 + 1] = a1;
}

// ---------------------------------------------------------------------------
// agg[i][:] = dinv[i]^2 * xw[i][:]   (self-loop term; also serves as the zero-init)
__global__ __launch_bounds__(256) void k_selfinit64(const float* __restrict__ dinv,
                                                    const float* __restrict__ xw,
                                                    float* __restrict__ agg) {
    int t = blockIdx.x * 256 + threadIdx.x;   // over N_NODES*64, exact multiple
    int i = t >> 6;
    float di = dinv[i];
    agg[t] = di * di * xw[t];
}

__global__ __launch_bounds__(256) void k_selfinit2(const float* __restrict__ dinv,
                                                   const float* __restrict__ xw,
                                                   float* __restrict__ agg) {
    int t = blockIdx.x * 256 + threadIdx.x;
    if (t < N_NODES * 2) {
        int i = t >> 1;
        float di = dinv[i];
        agg[t] = di * di * xw[t];
    }
}

// edge scatter, D=64: 16 lanes per edge, float4 gather + 4 atomics
__global__ __launch_bounds__(256) void k_scatter64(const int* __restrict__ src,
                                                   const int* __restrict__ dst,
                                                   const float* __restrict__ dinv,
                                                   const float* __restrict__ xw,
                                                   float* __restrict__ agg) {
    int t = blockIdx.x * 256 + threadIdx.x;
    int e = t >> 4;
    if (e >= N_EDGES) return;
    int l = t & 15;
    int s = src[e], d = dst[e];
    float norm = dinv[s] * dinv[d];
    float4 v = *reinterpret_cast<const float4*>(&xw[(size_t)s * 64 + l * 4]);
    float* o = &agg[(size_t)d * 64 + l * 4];
    atomicAdd(o + 0, norm * v.x);
    atomicAdd(o + 1, norm * v.y);
    atomicAdd(o + 2, norm * v.z);
    atomicAdd(o + 3, norm * v.w);
}

// edge scatter, D=2: 1 thread per edge
__global__ __launch_bounds__(256) void k_scatter2(const int* __restrict__ src,
                                                  const int* __restrict__ dst,
                                                  const float* __restrict__ dinv,
                                                  const float* __restrict__ xw,
                                                  float* __restrict__ agg) {
    int e = blockIdx.x * 256 + threadIdx.x;
    if (e >= N_EDGES) return;
    int s = src[e], d = dst[e];
    float norm = dinv[s] * dinv[d];
    float2 v = *reinterpret_cast<const float2*>(&xw[(size_t)s * 2]);
    float* o = &agg[(size_t)d * 2];
    atomicAdd(o + 0, norm * v.x);
    atomicAdd(o + 1, norm * v.y);
}

// ---------------------------------------------------------------------------
// pooling: psum[g][c] += agg3[i][c]; pcnt[g] += 1
__global__ __launch_bounds__(256) void k_pool(const int* __restrict__ batch,
                                              const float* __restrict__ agg3,
                                              float* __restrict__ psum,
                                              float* __restrict__ pcnt) {
    int i = blockIdx.x * 256 + threadIdx.x;
    if (i >= N_NODES) return;
    int g = batch[i];
    float2 v = *reinterpret_cast<const float2*>(&agg3[(size_t)i * 2]);
    atomicAdd(&psum[g * 2 + 0], v.x);
    atomicAdd(&psum[g * 2 + 1], v.y);
    atomicAdd(&pcnt[g], 1.0f);
}

// out[g][c] = (psum + cnt*b3) / max(cnt,1)   (cnt==0 -> 0, matching clip)
__global__ __launch_bounds__(256) void k_final(const float* __restrict__ psum,
                                               const float* __restrict__ pcnt,
                                               const float* __restrict__ b3,
                                               float* __restrict__ out) {
    int g = blockIdx.x * 256 + threadIdx.x;
    if (g >= N_GRAPHS) return;
    float c  = pcnt[g];
    float cc = fmaxf(c, 1.0f);
    out[g * 2 + 0] = (psum[g * 2 + 0] + c * b3[0]) / cc;
    out[g * 2 + 1] = (psum[g * 2 + 1] + c * b3[1]) / cc;
}

// ---------------------------------------------------------------------------
extern "C" void kernel_launch(void* const* d_in, const int* in_sizes, int n_in,
                              void* d_out, int out_size, void* d_ws, size_t ws_size,
                              hipStream_t stream) {
    const float* x    = (const float*)d_in[0];          // [50000,128]
    const int*   ei   = (const int*)d_in[1];            // [2,800000]
    const int*   batch= (const int*)d_in[2];            // [50000]
    const float* W1   = (const float*)d_in[3];          // [128,64]
    const float* b1   = (const float*)d_in[4];
    const float* W2   = (const float*)d_in[5];          // [64,64]
    const float* b2   = (const float*)d_in[6];
    const float* W3   = (const float*)d_in[7];          // [64,2]
    const float* b3   = (const float*)d_in[8];
    const int* src = ei;
    const int* dst = ei + N_EDGES;

    float* ws   = (float*)d_ws;
    float* dinv = ws;                       // 50000 (rounded region 51200)
    float* xw   = ws + 51200;               // 50000*64 = 3,200,000
    float* agg  = xw + 3200000;             // 3,200,000
    float* psum = agg + 3200000;            // 1024
    float* pcnt = psum + 1024;              // 512
    float* out  = (float*)d_out;            // [512,2]

    hipMemsetAsync(dinv, 0, N_NODES * sizeof(float), stream);
    hipMemsetAsync(psum, 0, (1024 + 512) * sizeof(float), stream);

    // degree -> dinv
    k_deg <<<(N_EDGES + 255) / 256, 256, 0, stream>>>(dst, dinv);
    k_dinv<<<(N_NODES + 255) / 256, 256, 0, stream>>>(dinv);

    // ---- layer 1: xw1 = x @ W1 ; agg1 = D^-1/2 A D^-1/2 xw1
    k_gemm64<128, false><<<N_NODES / 16, 256, 0, stream>>>(x, W1, nullptr, xw);
    k_selfinit64<<<(N_NODES * 64) / 256, 256, 0, stream>>>(dinv, xw, agg);
    k_scatter64<<<(N_EDGES * 16) / 256, 256, 0, stream>>>(src, dst, dinv, xw, agg);

    // ---- layer 2: xw2 = relu(agg1+b1) @ W2 ; agg2 = ...
    k_gemm64<64, true><<<N_NODES / 16, 256, 0, stream>>>(agg, W2, b1, xw);
    k_selfinit64<<<(N_NODES * 64) / 256, 256, 0, stream>>>(dinv, xw, agg + 0); // overwrite ok? no!
    // NOTE: selfinit writes agg from xw — agg1 already consumed by gemm above. safe.
    k_scatter64<<<(N_EDGES * 16) / 256, 256, 0, stream>>>(src, dst, dinv, xw, agg);

    // ---- layer 3: xw3 = relu(agg2+b2) @ W3 ; agg3 = ...
    // write xw3 into the xw buffer (xw2 no longer needed), agg3 into agg buffer
    k_gemm2<<<(N_NODES + 255) / 256, 256, 0, stream>>>(agg, W3, b2, xw);
    k_selfinit2<<<(N_NODES * 2 + 255) / 256, 256, 0, stream>>>(dinv, xw, agg);
    k_scatter2<<<(N_EDGES + 255) / 256, 256, 0, stream>>>(src, dst, dinv, xw, agg);

    // ---- pool
    k_pool <<<(N_NODES + 255) / 256, 256, 0, stream>>>(batch, agg, psum, pcnt);
    k_final<<<(N_GRAPHS + 255) / 256, 256, 0, stream>>>(psum, pcnt, b3, out);
}

// Round 4
// 404.801 us; speedup vs baseline: 4.2655x; 4.2655x over previous
//
#include <hip/hip_runtime.h>
#include <hip/hip_bf16.h>

#define N_NODES   50000
#define N_EDGES   800000
#define N_GRAPHS  512
#define IN_DIM    128
#define HIDDEN    64
#define NPAD      50176          // 196 * 256, padded node count for scan
#define NBLK      196            // scan blocks

// ---------------------------------------------------------------------------
// int degree histogram over dst (self-loop added analytically later)
__global__ __launch_bounds__(256) void k_degi(const int* __restrict__ dst,
                                              int* __restrict__ degi) {
    int e = blockIdx.x * 256 + threadIdx.x;
    if (e < N_EDGES) atomicAdd(&degi[dst[e]], 1);
}

__global__ __launch_bounds__(256) void k_dinv(const int* __restrict__ degi,
                                              float* __restrict__ dinv) {
    int i = blockIdx.x * 256 + threadIdx.x;
    if (i < N_NODES) dinv[i] = rsqrtf((float)degi[i] + 1.0f);
}

// ---------------------------------------------------------------------------
// two-level exclusive scan over degi[NPAD] -> offs
__global__ __launch_bounds__(256) void k_scan_block(const int* __restrict__ degi,
                                                    int* __restrict__ offs,
                                                    int* __restrict__ bsum) {
    __shared__ int sh[256];
    int tid = threadIdx.x;
    int i = blockIdx.x * 256 + tid;
    int v = degi[i];
    sh[tid] = v;
    __syncthreads();
    #pragma unroll
    for (int off = 1; off < 256; off <<= 1) {
        int t = (tid >= off) ? sh[tid - off] : 0;
        __syncthreads();
        sh[tid] += t;
        __syncthreads();
    }
    offs[i] = sh[tid] - v;                     // exclusive
    if (tid == 255) bsum[blockIdx.x] = sh[tid];
}

__global__ __launch_bounds__(256) void k_scan_bsum(int* __restrict__ bsum,
                                                   int* __restrict__ boff) {
    __shared__ int sh[256];
    int tid = threadIdx.x;
    int v = (tid < NBLK) ? bsum[tid] : 0;
    sh[tid] = v;
    __syncthreads();
    #pragma unroll
    for (int off = 1; off < 256; off <<= 1) {
        int t = (tid >= off) ? sh[tid - off] : 0;
        __syncthreads();
        sh[tid] += t;
        __syncthreads();
    }
    if (tid < NBLK) boff[tid] = sh[tid] - v;   // exclusive block offsets
}

__global__ __launch_bounds__(256) void k_scan_add(int* __restrict__ offs,
                                                  const int* __restrict__ boff) {
    int i = blockIdx.x * 256 + threadIdx.x;
    offs[i] += boff[blockIdx.x];
}

// fill CSR: csr_src[ offs[d] + k ] = src(e) for the k-th edge landing on d
__global__ __launch_bounds__(256) void k_fill(const int* __restrict__ src,
                                              const int* __restrict__ dst,
                                              const int* __restrict__ offs,
                                              int* __restrict__ cnt,
                                              int* __restrict__ csr_src) {
    int e = blockIdx.x * 256 + threadIdx.x;
    if (e >= N_EDGES) return;
    int d = dst[e];
    int pos = offs[d] + atomicAdd(&cnt[d], 1);
    csr_src[pos] = src[e];
}

// ---------------------------------------------------------------------------
// GEMM: out[N][64] = f(A)[N][K] @ W[K][64], f = identity or relu(x + bin)
template <int K, bool RELU_IN>
__global__ __launch_bounds__(256) void k_gemm64(const float* __restrict__ A,
                                                const float* __restrict__ W,
                                                const float* __restrict__ bin,
                                                float* __restrict__ out) {
    __shared__ float sW[K * 64];
    __shared__ float sA[16][K];
    const int tid = threadIdx.x;
    const int rowBase = blockIdx.x * 16;

    for (int i = tid; i < K * 64; i += 256) sW[i] = W[i];
    for (int i = tid; i < 16 * K; i += 256) {
        int r = i / K, k = i % K;
        int gr = rowBase + r;
        float v = (gr < N_NODES) ? A[gr * K + k] : 0.0f;
        if (RELU_IN) v = fmaxf(v + bin[k], 0.0f);
        sA[r][k] = v;
    }
    __syncthreads();

    const int c  = tid & 63;
    const int rb = tid >> 6;
    float acc0 = 0.f, acc1 = 0.f, acc2 = 0.f, acc3 = 0.f;
    for (int k = 0; k < K; ++k) {
        float w = sW[k * 64 + c];
        acc0 = fmaf(sA[rb + 0][k],  w, acc0);
        acc1 = fmaf(sA[rb + 4][k],  w, acc1);
        acc2 = fmaf(sA[rb + 8][k],  w, acc2);
        acc3 = fmaf(sA[rb + 12][k], w, acc3);
    }
    float acc[4] = {acc0, acc1, acc2, acc3};
    for (int j = 0; j < 4; ++j) {
        int r = rowBase + rb + j * 4;
        if (r < N_NODES) out[r * 64 + c] = acc[j];
    }
}

// out[N][2] = relu(A + b2) @ W3[64][2]
__global__ __launch_bounds__(256) void k_gemm2(const float* __restrict__ A,
                                               const float* __restrict__ W3,
                                               const float* __restrict__ b2,
                                               float* __restrict__ out) {
    __shared__ float sW[128];
    __shared__ float sB[64];
    int tid = threadIdx.x;
    if (tid < 128) sW[tid] = W3[tid];
    if (tid < 64)  sB[tid] = b2[tid];
    __syncthreads();
    int i = blockIdx.x * 256 + tid;
    if (i >= N_NODES) return;
    float a0 = 0.f, a1 = 0.f;
    const float* row = A + (size_t)i * 64;
    #pragma unroll
    for (int k = 0; k < 64; k += 4) {
        float4 v = *reinterpret_cast<const float4*>(row + k);
        float z;
        z = fmaxf(v.x + sB[k + 0], 0.f); a0 = fmaf(z, sW[(k+0)*2+0], a0); a1 = fmaf(z, sW[(k+0)*2+1], a1);
        z = fmaxf(v.y + sB[k + 1], 0.f); a0 = fmaf(z, sW[(k+1)*2+0], a0); a1 = fmaf(z, sW[(k+1)*2+1], a1);
        z = fmaxf(v.z + sB[k + 2], 0.f); a0 = fmaf(z, sW[(k+2)*2+0], a0); a1 = fmaf(z, sW[(k+2)*2+1], a1);
        z = fmaxf(v.w + sB[k + 3], 0.f); a0 = fmaf(z, sW[(k+3)*2+0], a0); a1 = fmaf(z, sW[(k+3)*2+1], a1);
    }
    out[i * 2 + 0] = a0;
    out[i * 2 + 1] = a1;
}

// ---------------------------------------------------------------------------
// gather aggregation D=64: one wave per node, lane = feature dim.
// acc init = self-loop term; loop CSR edges, 8-wide index prefetch for ILP.
__global__ __launch_bounds__(256) void k_gather64(const int* __restrict__ csr_src,
                                                  const int* __restrict__ offs,
                                                  const int* __restrict__ degi,
                                                  const float* __restrict__ dinv,
                                                  const float* __restrict__ xw,
                                                  float* __restrict__ agg) {
    int gid  = blockIdx.x * 256 + threadIdx.x;
    int node = gid >> 6;
    int lane = threadIdx.x & 63;
    if (node >= N_NODES) return;
    float dd = dinv[node];
    float acc = dd * dd * xw[(size_t)node * 64 + lane];
    int beg = offs[node];
    int n   = degi[node];
    int j = 0;
    for (; j + 7 < n; j += 8) {
        int   s[8];
        float nm[8];
        #pragma unroll
        for (int u = 0; u < 8; ++u) s[u] = csr_src[beg + j + u];
        #pragma unroll
        for (int u = 0; u < 8; ++u) nm[u] = dinv[s[u]] * dd;
        float v[8];
        #pragma unroll
        for (int u = 0; u < 8; ++u) v[u] = xw[(size_t)s[u] * 64 + lane];
        #pragma unroll
        for (int u = 0; u < 8; ++u) acc = fmaf(nm[u], v[u], acc);
    }
    for (; j < n; ++j) {
        int s = csr_src[beg + j];
        acc = fmaf(dinv[s] * dd, xw[(size_t)s * 64 + lane], acc);
    }
    agg[(size_t)node * 64 + lane] = acc;
}

// gather aggregation D=2: one thread per node
__global__ __launch_bounds__(256) void k_gather2(const int* __restrict__ csr_src,
                                                 const int* __restrict__ offs,
                                                 const int* __restrict__ degi,
                                                 const float* __restrict__ dinv,
                                                 const float* __restrict__ xw,
                                                 float* __restrict__ agg) {
    int node = blockIdx.x * 256 + threadIdx.x;
    if (node >= N_NODES) return;
    float dd = dinv[node];
    float2 v = *reinterpret_cast<const float2*>(&xw[(size_t)node * 2]);
    float a0 = dd * dd * v.x, a1 = dd * dd * v.y;
    int beg = offs[node];
    int n   = degi[node];
    for (int j = 0; j < n; ++j) {
        int s = csr_src[beg + j];
        float nm = dinv[s] * dd;
        float2 u = *reinterpret_cast<const float2*>(&xw[(size_t)s * 2]);
        a0 = fmaf(nm, u.x, a0);
        a1 = fmaf(nm, u.y, a1);
    }
    agg[(size_t)node * 2 + 0] = a0;
    agg[(size_t)node * 2 + 1] = a1;
}

// ---------------------------------------------------------------------------
__global__ __launch_bounds__(256) void k_pool(const int* __restrict__ batch,
                                              const float* __restrict__ agg3,
                                              float* __restrict__ psum,
                                              float* __restrict__ pcnt) {
    int i = blockIdx.x * 256 + threadIdx.x;
    if (i >= N_NODES) return;
    int g = batch[i];
    float2 v = *reinterpret_cast<const float2*>(&agg3[(size_t)i * 2]);
    atomicAdd(&psum[g * 2 + 0], v.x);
    atomicAdd(&psum[g * 2 + 1], v.y);
    atomicAdd(&pcnt[g], 1.0f);
}

__global__ __launch_bounds__(256) void k_final(const float* __restrict__ psum,
                                               const float* __restrict__ pcnt,
                                               const float* __restrict__ b3,
                                               float* __restrict__ out) {
    int g = blockIdx.x * 256 + threadIdx.x;
    if (g >= N_GRAPHS) return;
    float c  = pcnt[g];
    float cc = fmaxf(c, 1.0f);
    out[g * 2 + 0] = (psum[g * 2 + 0] + c * b3[0]) / cc;
    out[g * 2 + 1] = (psum[g * 2 + 1] + c * b3[1]) / cc;
}

// ---------------------------------------------------------------------------
extern "C" void kernel_launch(void* const* d_in, const int* in_sizes, int n_in,
                              void* d_out, int out_size, void* d_ws, size_t ws_size,
                              hipStream_t stream) {
    const float* x     = (const float*)d_in[0];
    const int*   ei    = (const int*)d_in[1];
    const int*   batch = (const int*)d_in[2];
    const float* W1    = (const float*)d_in[3];
    const float* b1    = (const float*)d_in[4];
    const float* W2    = (const float*)d_in[5];
    const float* b2    = (const float*)d_in[6];
    const float* W3    = (const float*)d_in[7];
    const float* b3    = (const float*)d_in[8];
    const int* src = ei;
    const int* dst = ei + N_EDGES;

    float* ws   = (float*)d_ws;
    float* dinv = ws;                            // NPAD floats
    int*   degi = (int*)(dinv + NPAD);           // NPAD
    int*   offs = degi + NPAD;                   // NPAD
    int*   cnt  = offs + NPAD;                   // NPAD
    int*   bsum = cnt + NPAD;                    // 256
    int*   boff = bsum + 256;                    // 256
    int*   csr  = boff + 256;                    // N_EDGES
    float* xw   = (float*)(csr + N_EDGES);       // 3,200,000
    float* agg  = xw + (size_t)N_NODES * 64;     // 3,200,000
    float* psum = agg + (size_t)N_NODES * 64;    // 1024
    float* pcnt = psum + 1024;                   // 512
    float* out  = (float*)d_out;

    hipMemsetAsync(degi, 0, NPAD * sizeof(int), stream);
    hipMemsetAsync(cnt,  0, NPAD * sizeof(int), stream);
    hipMemsetAsync(psum, 0, (1024 + 512) * sizeof(float), stream);

    // ---- graph preprocessing: degrees, dinv, CSR
    k_degi<<<(N_EDGES + 255) / 256, 256, 0, stream>>>(dst, degi);
    k_dinv<<<(N_NODES + 255) / 256, 256, 0, stream>>>(degi, dinv);
    k_scan_block<<<NBLK, 256, 0, stream>>>(degi, offs, bsum);
    k_scan_bsum<<<1, 256, 0, stream>>>(bsum, boff);
    k_scan_add<<<NBLK, 256, 0, stream>>>(offs, boff);
    k_fill<<<(N_EDGES + 255) / 256, 256, 0, stream>>>(src, dst, offs, cnt, csr);

    // ---- layer 1
    k_gemm64<128, false><<<(N_NODES + 15) / 16, 256, 0, stream>>>(x, W1, nullptr, xw);
    k_gather64<<<(N_NODES * 64) / 256, 256, 0, stream>>>(csr, offs, degi, dinv, xw, agg);

    // ---- layer 2
    k_gemm64<64, true><<<(N_NODES + 15) / 16, 256, 0, stream>>>(agg, W2, b1, xw);
    k_gather64<<<(N_NODES * 64) / 256, 256, 0, stream>>>(csr, offs, degi, dinv, xw, agg);

    // ---- layer 3
    k_gemm2<<<(N_NODES + 255) / 256, 256, 0, stream>>>(agg, W3, b2, xw);
    k_gather2<<<(N_NODES + 255) / 256, 256, 0, stream>>>(csr, offs, degi, dinv, xw, agg);

    // ---- pool
    k_pool <<<(N_NODES + 255) / 256, 256, 0, stream>>>(batch, agg, psum, pcnt);
    k_final<<<(N_GRAPHS + 255) / 256, 256, 0, stream>>>(psum, pcnt, b3, out);
}

// Round 6
// 351.600 us; speedup vs baseline: 4.9109x; 1.1513x over previous
//
#include <hip/hip_runtime.h>
#include <hip/hip_bf16.h>

#define N_NODES   50000
#define N_EDGES   800000
#define N_GRAPHS  512
#define IN_DIM    128
#define HIDDEN    64
#define NPAD      50176          // 196 * 256, padded node count for scan
#define NBLK      196            // scan blocks

// ---------------------------------------------------------------------------
__global__ __launch_bounds__(256) void k_degi(const int* __restrict__ dst,
                                              int* __restrict__ degi) {
    int e = blockIdx.x * 256 + threadIdx.x;
    if (e < N_EDGES) atomicAdd(&degi[dst[e]], 1);
}

__global__ __launch_bounds__(256) void k_dinv(const int* __restrict__ degi,
                                              float* __restrict__ dinv) {
    int i = blockIdx.x * 256 + threadIdx.x;
    if (i < N_NODES) dinv[i] = rsqrtf((float)degi[i] + 1.0f);
}

// ---------------------------------------------------------------------------
// two-level exclusive scan over degi[NPAD] -> offs
__global__ __launch_bounds__(256) void k_scan_block(const int* __restrict__ degi,
                                                    int* __restrict__ offs,
                                                    int* __restrict__ bsum) {
    __shared__ int sh[256];
    int tid = threadIdx.x;
    int i = blockIdx.x * 256 + tid;
    int v = degi[i];
    sh[tid] = v;
    __syncthreads();
    #pragma unroll
    for (int off = 1; off < 256; off <<= 1) {
        int t = (tid >= off) ? sh[tid - off] : 0;
        __syncthreads();
        sh[tid] += t;
        __syncthreads();
    }
    offs[i] = sh[tid] - v;                     // exclusive
    if (tid == 255) bsum[blockIdx.x] = sh[tid];
}

__global__ __launch_bounds__(256) void k_scan_bsum(int* __restrict__ bsum,
                                                   int* __restrict__ boff) {
    __shared__ int sh[256];
    int tid = threadIdx.x;
    int v = (tid < NBLK) ? bsum[tid] : 0;
    sh[tid] = v;
    __syncthreads();
    #pragma unroll
    for (int off = 1; off < 256; off <<= 1) {
        int t = (tid >= off) ? sh[tid - off] : 0;
        __syncthreads();
        sh[tid] += t;
        __syncthreads();
    }
    if (tid < NBLK) boff[tid] = sh[tid] - v;   // exclusive block offsets
}

__global__ __launch_bounds__(256) void k_scan_add(int* __restrict__ offs,
                                                  const int* __restrict__ boff) {
    int i = blockIdx.x * 256 + threadIdx.x;
    offs[i] += boff[blockIdx.x];
}

// fill CSR: csr_src[ offs[d] + k ] = src(e) for the k-th edge landing on d
__global__ __launch_bounds__(256) void k_fill(const int* __restrict__ src,
                                              const int* __restrict__ dst,
                                              const int* __restrict__ offs,
                                              int* __restrict__ cnt,
                                              int* __restrict__ csr_src) {
    int e = blockIdx.x * 256 + threadIdx.x;
    if (e >= N_EDGES) return;
    int d = dst[e];
    int pos = offs[d] + atomicAdd(&cnt[d], 1);
    csr_src[pos] = src[e];
}

// ---------------------------------------------------------------------------
// Register-tiled GEMM: out[N][64] = dinv[row] * ( f(A)[N][K] @ W[K][64] )
// f = identity or relu(x + bin).  Block: 64 rows x 64 cols, 256 threads,
// each thread a 4x4 micro-tile.  K processed in 64-chunks.
template <int K, bool RELU_IN>
__global__ __launch_bounds__(256) void k_gemm64t(const float* __restrict__ A,
                                                 const float* __restrict__ W,
                                                 const float* __restrict__ bin,
                                                 const float* __restrict__ dinv,
                                                 float* __restrict__ out) {
    __shared__ float sA[64][65];   // [row][k], pad 65 -> conflict-free
    __shared__ float sW[64][64];   // [k][col] chunk
    __shared__ float sB[64];

    const int tid = threadIdx.x;
    const int rowBase = blockIdx.x * 64;
    const int c0 = (tid & 15) * 4;
    const int r0 = (tid >> 4) * 4;

    if (RELU_IN && tid < 64) sB[tid] = bin[tid];

    float acc[4][4];
    #pragma unroll
    for (int j = 0; j < 4; ++j)
        #pragma unroll
        for (int c = 0; c < 4; ++c) acc[j][c] = 0.0f;

    for (int kc = 0; kc < K; kc += 64) {
        __syncthreads();
        // stage W chunk: 64x64 floats = 1024 float4, 4 per thread
        #pragma unroll
        for (int p = 0; p < 4; ++p) {
            int i = p * 256 + tid;          // float4 id
            int k  = i >> 4;
            int cq = i & 15;
            *reinterpret_cast<float4*>(&sW[k][cq * 4]) =
                *reinterpret_cast<const float4*>(&W[(size_t)(kc + k) * 64 + cq * 4]);
        }
        // stage A chunk: 64 rows x 64 k = 1024 float4, 4 per thread
        #pragma unroll
        for (int p = 0; p < 4; ++p) {
            int i = p * 256 + tid;
            int row = i >> 4;
            int kq  = i & 15;
            int gr = rowBase + row;
            float4 v = make_float4(0.f, 0.f, 0.f, 0.f);
            if (gr < N_NODES)
                v = *reinterpret_cast<const float4*>(&A[(size_t)gr * K + kc + kq * 4]);
            if (RELU_IN) {
                v.x = fmaxf(v.x + sB[kq * 4 + 0], 0.f);
                v.y = fmaxf(v.y + sB[kq * 4 + 1], 0.f);
                v.z = fmaxf(v.z + sB[kq * 4 + 2], 0.f);
                v.w = fmaxf(v.w + sB[kq * 4 + 3], 0.f);
            }
            sA[row][kq * 4 + 0] = v.x;
            sA[row][kq * 4 + 1] = v.y;
            sA[row][kq * 4 + 2] = v.z;
            sA[row][kq * 4 + 3] = v.w;
        }
        __syncthreads();

        #pragma unroll 8
        for (int k = 0; k < 64; ++k) {
            float4 w4 = *reinterpret_cast<const float4*>(&sW[k][c0]);
            float a0 = sA[r0 + 0][k];
            float a1 = sA[r0 + 1][k];
            float a2 = sA[r0 + 2][k];
            float a3 = sA[r0 + 3][k];
            acc[0][0] = fmaf(a0, w4.x, acc[0][0]);
            acc[0][1] = fmaf(a0, w4.y, acc[0][1]);
            acc[0][2] = fmaf(a0, w4.z, acc[0][2]);
            acc[0][3] = fmaf(a0, w4.w, acc[0][3]);
            acc[1][0] = fmaf(a1, w4.x, acc[1][0]);
            acc[1][1] = fmaf(a1, w4.y, acc[1][1]);
            acc[1][2] = fmaf(a1, w4.z, acc[1][2]);
            acc[1][3] = fmaf(a1, w4.w, acc[1][3]);
            acc[2][0] = fmaf(a2, w4.x, acc[2][0]);
            acc[2][1] = fmaf(a2, w4.y, acc[2][1]);
            acc[2][2] = fmaf(a2, w4.z, acc[2][2]);
            acc[2][3] = fmaf(a2, w4.w, acc[2][3]);
            acc[3][0] = fmaf(a3, w4.x, acc[3][0]);
            acc[3][1] = fmaf(a3, w4.y, acc[3][1]);
            acc[3][2] = fmaf(a3, w4.z, acc[3][2]);
            acc[3][3] = fmaf(a3, w4.w, acc[3][3]);
        }
    }

    // epilogue: scale row by dinv, store float4
    #pragma unroll
    for (int j = 0; j < 4; ++j) {
        int gr = rowBase + r0 + j;
        if (gr < N_NODES) {
            float di = dinv[gr];
            float4 o;
            o.x = di * acc[j][0];
            o.y = di * acc[j][1];
            o.z = di * acc[j][2];
            o.w = di * acc[j][3];
            *reinterpret_cast<float4*>(&out[(size_t)gr * 64 + c0]) = o;
        }
    }
}

// out[N][2] = dinv[i] * ( relu(A + b2) @ W3[64][2] )
__global__ __launch_bounds__(256) void k_gemm2(const float* __restrict__ A,
                                               const float* __restrict__ W3,
                                               const float* __restrict__ b2,
                                               const float* __restrict__ dinv,
                                               float* __restrict__ out) {
    __shared__ float sW[128];
    __shared__ float sB[64];
    int tid = threadIdx.x;
    if (tid < 128) sW[tid] = W3[tid];
    if (tid < 64)  sB[tid] = b2[tid];
    __syncthreads();
    int i = blockIdx.x * 256 + tid;
    if (i >= N_NODES) return;
    float a0 = 0.f, a1 = 0.f;
    const float* row = A + (size_t)i * 64;
    #pragma unroll
    for (int k = 0; k < 64; k += 4) {
        float4 v = *reinterpret_cast<const float4*>(row + k);
        float z;
        z = fmaxf(v.x + sB[k + 0], 0.f); a0 = fmaf(z, sW[(k+0)*2+0], a0); a1 = fmaf(z, sW[(k+0)*2+1], a1);
        z = fmaxf(v.y + sB[k + 1], 0.f); a0 = fmaf(z, sW[(k+1)*2+0], a0); a1 = fmaf(z, sW[(k+1)*2+1], a1);
        z = fmaxf(v.z + sB[k + 2], 0.f); a0 = fmaf(z, sW[(k+2)*2+0], a0); a1 = fmaf(z, sW[(k+2)*2+1], a1);
        z = fmaxf(v.w + sB[k + 3], 0.f); a0 = fmaf(z, sW[(k+3)*2+0], a0); a1 = fmaf(z, sW[(k+3)*2+1], a1);
    }
    float di = dinv[i];
    out[i * 2 + 0] = di * a0;
    out[i * 2 + 1] = di * a1;
}

// ---------------------------------------------------------------------------
// gather aggregation D=64: one wave per node, lane = feature dim.
// yw is pre-scaled by dinv[src]; out = dinv[node] * (yw[node] + sum yw[s]).
__global__ __launch_bounds__(256) void k_gather64(const int* __restrict__ csr_src,
                                                  const int* __restrict__ offs,
                                                  const int* __restrict__ degi,
                                                  const float* __restrict__ dinv,
                                                  const float* __restrict__ yw,
                                                  float* __restrict__ agg) {
    int gid  = blockIdx.x * 256 + threadIdx.x;
    int node = gid >> 6;
    int lane = threadIdx.x & 63;
    if (node >= N_NODES) return;
    float acc = yw[(size_t)node * 64 + lane];   // self-loop term (pre-scaled)
    int beg = offs[node];
    int n   = degi[node];
    int j = 0;
    for (; j + 7 < n; j += 8) {
        int s[8];
        #pragma unroll
        for (int u = 0; u < 8; ++u) s[u] = csr_src[beg + j + u];
        float v[8];
        #pragma unroll
        for (int u = 0; u < 8; ++u) v[u] = yw[(size_t)s[u] * 64 + lane];
        #pragma unroll
        for (int u = 0; u < 8; ++u) acc += v[u];
    }
    for (; j < n; ++j) {
        int s = csr_src[beg + j];
        acc += yw[(size_t)s * 64 + lane];
    }
    agg[(size_t)node * 64 + lane] = dinv[node] * acc;
}

// gather aggregation D=2: one thread per node
__global__ __launch_bounds__(256) void k_gather2(const int* __restrict__ csr_src,
                                                 const int* __restrict__ offs,
                                                 const int* __restrict__ degi,
                                                 const float* __restrict__ dinv,
                                                 const float* __restrict__ yw,
                                                 float* __restrict__ agg) {
    int node = blockIdx.x * 256 + threadIdx.x;
    if (node >= N_NODES) return;
    float2 v = *reinterpret_cast<const float2*>(&yw[(size_t)node * 2]);
    float a0 = v.x, a1 = v.y;
    int beg = offs[node];
    int n   = degi[node];
    for (int j = 0; j < n; ++j) {
        int s = csr_src[beg + j];
        float2 u = *reinterpret_cast<const float2*>(&yw[(size_t)s * 2]);
        a0 += u.x;
        a1 += u.y;
    }
    float di = dinv[node];
    agg[(size_t)node * 2 + 0] = di * a0;
    agg[(size_t)node * 2 + 1] = di * a1;
}

// ---------------------------------------------------------------------------
__global__ __launch_bounds__(256) void k_pool(const int* __restrict__ batch,
                                              const float* __restrict__ agg3,
                                              float* __restrict__ psum,
                                              float* __restrict__ pcnt) {
    int i = blockIdx.x * 256 + threadIdx.x;
    if (i >= N_NODES) return;
    int g = batch[i];
    float2 v = *reinterpret_cast<const float2*>(&agg3[(size_t)i * 2]);
    atomicAdd(&psum[g * 2 + 0], v.x);
    atomicAdd(&psum[g * 2 + 1], v.y);
    atomicAdd(&pcnt[g], 1.0f);
}

__global__ __launch_bounds__(256) void k_final(const float* __restrict__ psum,
                                               const float* __restrict__ pcnt,
                                               const float* __restrict__ b3,
                                               float* __restrict__ out) {
    int g = blockIdx.x * 256 + threadIdx.x;
    if (g >= N_GRAPHS) return;
    float c  = pcnt[g];
    float cc = fmaxf(c, 1.0f);
    out[g * 2 + 0] = (psum[g * 2 + 0] + c * b3[0]) / cc;
    out[g * 2 + 1] = (psum[g * 2 + 1] + c * b3[1]) / cc;
}

// ---------------------------------------------------------------------------
extern "C" void kernel_launch(void* const* d_in, const int* in_sizes, int n_in,
                              void* d_out, int out_size, void* d_ws, size_t ws_size,
                              hipStream_t stream) {
    const float* x     = (const float*)d_in[0];
    const int*   ei    = (const int*)d_in[1];
    const int*   batch = (const int*)d_in[2];
    const float* W1    = (const float*)d_in[3];
    const float* b1    = (const float*)d_in[4];
    const float* W2    = (const float*)d_in[5];
    const float* b2    = (const float*)d_in[6];
    const float* W3    = (const float*)d_in[7];
    const float* b3    = (const float*)d_in[8];
    const int* src = ei;
    const int* dst = ei + N_EDGES;

    float* ws   = (float*)d_ws;
    float* dinv = ws;                            // NPAD floats
    int*   degi = (int*)(dinv + NPAD);           // NPAD
    int*   offs = degi + NPAD;                   // NPAD
    int*   cnt  = offs + NPAD;                   // NPAD
    int*   bsum = cnt + NPAD;                    // 256
    int*   boff = bsum + 256;                    // 256
    int*   csr  = boff + 256;                    // N_EDGES
    float* xw   = (float*)(csr + N_EDGES);       // 3,200,000
    float* agg  = xw + (size_t)N_NODES * 64;     // 3,200,000
    float* psum = agg + (size_t)N_NODES * 64;    // 1024
    float* pcnt = psum + 1024;                   // 512
    float* out  = (float*)d_out;

    hipMemsetAsync(degi, 0, NPAD * sizeof(int), stream);
    hipMemsetAsync(cnt,  0, NPAD * sizeof(int), stream);
    hipMemsetAsync(psum, 0, (1024 + 512) * sizeof(float), stream);

    // ---- graph preprocessing: degrees, dinv, CSR
    k_degi<<<(N_EDGES + 255) / 256, 256, 0, stream>>>(dst, degi);
    k_dinv<<<(N_NODES + 255) / 256, 256, 0, stream>>>(degi, dinv);
    k_scan_block<<<NBLK, 256, 0, stream>>>(degi, offs, bsum);
    k_scan_bsum<<<1, 256, 0, stream>>>(bsum, boff);
    k_scan_add<<<NBLK, 256, 0, stream>>>(offs, boff);
    k_fill<<<(N_EDGES + 255) / 256, 256, 0, stream>>>(src, dst, offs, cnt, csr);

    // ---- layer 1: yw1 = dinv * (x @ W1); agg1 = dinv * (self + gather)
    k_gemm64t<128, false><<<(N_NODES + 63) / 64, 256, 0, stream>>>(x, W1, nullptr, dinv, xw);
    k_gather64<<<(N_NODES * 64) / 256, 256, 0, stream>>>(csr, offs, degi, dinv, xw, agg);

    // ---- layer 2
    k_gemm64t<64, true><<<(N_NODES + 63) / 64, 256, 0, stream>>>(agg, W2, b1, dinv, xw);
    k_gather64<<<(N_NODES * 64) / 256, 256, 0, stream>>>(csr, offs, degi, dinv, xw, agg);

    // ---- layer 3
    k_gemm2<<<(N_NODES + 255) / 256, 256, 0, stream>>>(agg, W3, b2, dinv, xw);
    k_gather2<<<(N_NODES + 255) / 256, 256, 0, stream>>>(csr, offs, degi, dinv, xw, agg);

    // ---- pool
    k_pool <<<(N_NODES + 255) / 256, 256, 0, stream>>>(batch, agg, psum, pcnt);
    k_final<<<(N_GRAPHS + 255) / 256, 256, 0, stream>>>(psum, pcnt, b3, out);
}

// Round 7
// 300.846 us; speedup vs baseline: 5.7394x; 1.1687x over previous
//
#include <hip/hip_runtime.h>
#include <hip/hip_bf16.h>

#define N_NODES   50000
#define N_EDGES   800000
#define N_GRAPHS  512
#define IN_DIM    128
#define HIDDEN    64
#define NPAD      50176          // 196 * 256, padded node count for scan
#define NBLK      196            // scan blocks

// ---------------------------------------------------------------------------
__global__ __launch_bounds__(256) void k_degi(const int* __restrict__ dst,
                                              int* __restrict__ degi) {
    int e = blockIdx.x * 256 + threadIdx.x;
    if (e < N_EDGES) atomicAdd(&degi[dst[e]], 1);
}

__global__ __launch_bounds__(256) void k_dinv(const int* __restrict__ degi,
                                              float* __restrict__ dinv) {
    int i = blockIdx.x * 256 + threadIdx.x;
    if (i < N_NODES) dinv[i] = rsqrtf((float)degi[i] + 1.0f);
}

// ---------------------------------------------------------------------------
// two-level exclusive scan over degi[NPAD] -> offs
__global__ __launch_bounds__(256) void k_scan_block(const int* __restrict__ degi,
                                                    int* __restrict__ offs,
                                                    int* __restrict__ bsum) {
    __shared__ int sh[256];
    int tid = threadIdx.x;
    int i = blockIdx.x * 256 + tid;
    int v = degi[i];
    sh[tid] = v;
    __syncthreads();
    #pragma unroll
    for (int off = 1; off < 256; off <<= 1) {
        int t = (tid >= off) ? sh[tid - off] : 0;
        __syncthreads();
        sh[tid] += t;
        __syncthreads();
    }
    offs[i] = sh[tid] - v;                     // exclusive
    if (tid == 255) bsum[blockIdx.x] = sh[tid];
}

__global__ __launch_bounds__(256) void k_scan_bsum(int* __restrict__ bsum,
                                                   int* __restrict__ boff) {
    __shared__ int sh[256];
    int tid = threadIdx.x;
    int v = (tid < NBLK) ? bsum[tid] : 0;
    sh[tid] = v;
    __syncthreads();
    #pragma unroll
    for (int off = 1; off < 256; off <<= 1) {
        int t = (tid >= off) ? sh[tid - off] : 0;
        __syncthreads();
        sh[tid] += t;
        __syncthreads();
    }
    if (tid < NBLK) boff[tid] = sh[tid] - v;   // exclusive block offsets
}

__global__ __launch_bounds__(256) void k_scan_add(int* __restrict__ offs,
                                                  const int* __restrict__ boff) {
    int i = blockIdx.x * 256 + threadIdx.x;
    offs[i] += boff[blockIdx.x];
}

// fill CSR: csr_src[ offs[d] + k ] = src(e) for the k-th edge landing on d
__global__ __launch_bounds__(256) void k_fill(const int* __restrict__ src,
                                              const int* __restrict__ dst,
                                              const int* __restrict__ offs,
                                              int* __restrict__ cnt,
                                              int* __restrict__ csr_src) {
    int e = blockIdx.x * 256 + threadIdx.x;
    if (e >= N_EDGES) return;
    int d = dst[e];
    int pos = offs[d] + atomicAdd(&cnt[d], 1);
    csr_src[pos] = src[e];
}

// ---------------------------------------------------------------------------
// Register-tiled GEMM: out[N][64] = dinv[row] * ( f(A)[N][K] @ W[K][64] )
// f = identity or relu(x + bin).  Block: 64 rows x 64 cols, 256 threads,
// each thread a 4x4 micro-tile.  K processed in 64-chunks.
template <int K, bool RELU_IN>
__global__ __launch_bounds__(256) void k_gemm64t(const float* __restrict__ A,
                                                 const float* __restrict__ W,
                                                 const float* __restrict__ bin,
                                                 const float* __restrict__ dinv,
                                                 float* __restrict__ out) {
    __shared__ float sA[64][65];   // [row][k], pad 65 -> conflict-free
    __shared__ float sW[64][64];   // [k][col] chunk
    __shared__ float sB[64];

    const int tid = threadIdx.x;
    const int rowBase = blockIdx.x * 64;
    const int c0 = (tid & 15) * 4;
    const int r0 = (tid >> 4) * 4;

    if (RELU_IN && tid < 64) sB[tid] = bin[tid];

    float acc[4][4];
    #pragma unroll
    for (int j = 0; j < 4; ++j)
        #pragma unroll
        for (int c = 0; c < 4; ++c) acc[j][c] = 0.0f;

    for (int kc = 0; kc < K; kc += 64) {
        __syncthreads();
        // stage W chunk: 64x64 floats = 1024 float4, 4 per thread
        #pragma unroll
        for (int p = 0; p < 4; ++p) {
            int i = p * 256 + tid;          // float4 id
            int k  = i >> 4;
            int cq = i & 15;
            *reinterpret_cast<float4*>(&sW[k][cq * 4]) =
                *reinterpret_cast<const float4*>(&W[(size_t)(kc + k) * 64 + cq * 4]);
        }
        // stage A chunk: 64 rows x 64 k = 1024 float4, 4 per thread
        #pragma unroll
        for (int p = 0; p < 4; ++p) {
            int i = p * 256 + tid;
            int row = i >> 4;
            int kq  = i & 15;
            int gr = rowBase + row;
            float4 v = make_float4(0.f, 0.f, 0.f, 0.f);
            if (gr < N_NODES)
                v = *reinterpret_cast<const float4*>(&A[(size_t)gr * K + kc + kq * 4]);
            if (RELU_IN) {
                v.x = fmaxf(v.x + sB[kq * 4 + 0], 0.f);
                v.y = fmaxf(v.y + sB[kq * 4 + 1], 0.f);
                v.z = fmaxf(v.z + sB[kq * 4 + 2], 0.f);
                v.w = fmaxf(v.w + sB[kq * 4 + 3], 0.f);
            }
            sA[row][kq * 4 + 0] = v.x;
            sA[row][kq * 4 + 1] = v.y;
            sA[row][kq * 4 + 2] = v.z;
            sA[row][kq * 4 + 3] = v.w;
        }
        __syncthreads();

        #pragma unroll 8
        for (int k = 0; k < 64; ++k) {
            float4 w4 = *reinterpret_cast<const float4*>(&sW[k][c0]);
            float a0 = sA[r0 + 0][k];
            float a1 = sA[r0 + 1][k];
            float a2 = sA[r0 + 2][k];
            float a3 = sA[r0 + 3][k];
            acc[0][0] = fmaf(a0, w4.x, acc[0][0]);
            acc[0][1] = fmaf(a0, w4.y, acc[0][1]);
            acc[0][2] = fmaf(a0, w4.z, acc[0][2]);
            acc[0][3] = fmaf(a0, w4.w, acc[0][3]);
            acc[1][0] = fmaf(a1, w4.x, acc[1][0]);
            acc[1][1] = fmaf(a1, w4.y, acc[1][1]);
            acc[1][2] = fmaf(a1, w4.z, acc[1][2]);
            acc[1][3] = fmaf(a1, w4.w, acc[1][3]);
            acc[2][0] = fmaf(a2, w4.x, acc[2][0]);
            acc[2][1] = fmaf(a2, w4.y, acc[2][1]);
            acc[2][2] = fmaf(a2, w4.z, acc[2][2]);
            acc[2][3] = fmaf(a2, w4.w, acc[2][3]);
            acc[3][0] = fmaf(a3, w4.x, acc[3][0]);
            acc[3][1] = fmaf(a3, w4.y, acc[3][1]);
            acc[3][2] = fmaf(a3, w4.z, acc[3][2]);
            acc[3][3] = fmaf(a3, w4.w, acc[3][3]);
        }
    }

    // epilogue: scale row by dinv, store float4
    #pragma unroll
    for (int j = 0; j < 4; ++j) {
        int gr = rowBase + r0 + j;
        if (gr < N_NODES) {
            float di = dinv[gr];
            float4 o;
            o.x = di * acc[j][0];
            o.y = di * acc[j][1];
            o.z = di * acc[j][2];
            o.w = di * acc[j][3];
            *reinterpret_cast<float4*>(&out[(size_t)gr * 64 + c0]) = o;
        }
    }
}

// out[N][2] = dinv[i] * ( relu(A + b2) @ W3[64][2] )
__global__ __launch_bounds__(256) void k_gemm2(const float* __restrict__ A,
                                               const float* __restrict__ W3,
                                               const float* __restrict__ b2,
                                               const float* __restrict__ dinv,
                                               float* __restrict__ out) {
    __shared__ float sW[128];
    __shared__ float sB[64];
    int tid = threadIdx.x;
    if (tid < 128) sW[tid] = W3[tid];
    if (tid < 64)  sB[tid] = b2[tid];
    __syncthreads();
    int i = blockIdx.x * 256 + tid;
    if (i >= N_NODES) return;
    float a0 = 0.f, a1 = 0.f;
    const float* row = A + (size_t)i * 64;
    #pragma unroll
    for (int k = 0; k < 64; k += 4) {
        float4 v = *reinterpret_cast<const float4*>(row + k);
        float z;
        z = fmaxf(v.x + sB[k + 0], 0.f); a0 = fmaf(z, sW[(k+0)*2+0], a0); a1 = fmaf(z, sW[(k+0)*2+1], a1);
        z = fmaxf(v.y + sB[k + 1], 0.f); a0 = fmaf(z, sW[(k+1)*2+0], a0); a1 = fmaf(z, sW[(k+1)*2+1], a1);
        z = fmaxf(v.z + sB[k + 2], 0.f); a0 = fmaf(z, sW[(k+2)*2+0], a0); a1 = fmaf(z, sW[(k+2)*2+1], a1);
        z = fmaxf(v.w + sB[k + 3], 0.f); a0 = fmaf(z, sW[(k+3)*2+0], a0); a1 = fmaf(z, sW[(k+3)*2+1], a1);
    }
    float di = dinv[i];
    out[i * 2 + 0] = di * a0;
    out[i * 2 + 1] = di * a1;
}

// ---------------------------------------------------------------------------
// gather aggregation D=64: one wave per node, lane = feature dim.
// yw is pre-scaled by dinv[src]; out = dinv[node] * (yw[node] + sum yw[s]).
__global__ __launch_bounds__(256) void k_gather64(const int* __restrict__ csr_src,
                                                  const int* __restrict__ offs,
                                                  const int* __restrict__ degi,
                                                  const float* __restrict__ dinv,
                                                  const float* __restrict__ yw,
                                                  float* __restrict__ agg) {
    int gid  = blockIdx.x * 256 + threadIdx.x;
    int node = gid >> 6;
    int lane = threadIdx.x & 63;
    if (node >= N_NODES) return;
    float acc = yw[(size_t)node * 64 + lane];   // self-loop term (pre-scaled)
    int beg = offs[node];
    int n   = degi[node];
    int j = 0;
    for (; j + 7 < n; j += 8) {
        int s[8];
        #pragma unroll
        for (int u = 0; u < 8; ++u) s[u] = csr_src[beg + j + u];
        float v[8];
        #pragma unroll
        for (int u = 0; u < 8; ++u) v[u] = yw[(size_t)s[u] * 64 + lane];
        #pragma unroll
        for (int u = 0; u < 8; ++u) acc += v[u];
    }
    for (; j < n; ++j) {
        int s = csr_src[beg + j];
        acc += yw[(size_t)s * 64 + lane];
    }
    agg[(size_t)node * 64 + lane] = dinv[node] * acc;
}

// ---------------------------------------------------------------------------
// Fused layer-3 gather + pooling.  Blocks cover 256 consecutive nodes; batch
// is sorted, so a block spans only a handful of graph ids.  Per-node result
// goes into LDS per-graph bins (LDS atomics), then one global atomic per
// (block, graph) — ~2.4K global atomics instead of 150K contended ones.
__global__ __launch_bounds__(256) void k_gather2pool(const int* __restrict__ csr_src,
                                                     const int* __restrict__ offs,
                                                     const int* __restrict__ degi,
                                                     const float* __restrict__ dinv,
                                                     const float* __restrict__ yw,
                                                     const int* __restrict__ batch,
                                                     float* __restrict__ psum,
                                                     float* __restrict__ pcnt) {
    __shared__ float ls0[N_GRAPHS];
    __shared__ float ls1[N_GRAPHS];
    __shared__ float lc [N_GRAPHS];
    int tid = threadIdx.x;
    #pragma unroll
    for (int g = tid; g < N_GRAPHS; g += 256) {
        ls0[g] = 0.f; ls1[g] = 0.f; lc[g] = 0.f;
    }
    __syncthreads();

    int node = blockIdx.x * 256 + tid;
    if (node < N_NODES) {
        float2 v = *reinterpret_cast<const float2*>(&yw[(size_t)node * 2]);
        float a0 = v.x, a1 = v.y;
        int beg = offs[node];
        int n   = degi[node];
        for (int j = 0; j < n; ++j) {
            int s = csr_src[beg + j];
            float2 u = *reinterpret_cast<const float2*>(&yw[(size_t)s * 2]);
            a0 += u.x;
            a1 += u.y;
        }
        float di = dinv[node];
        int g = batch[node];
        atomicAdd(&ls0[g], di * a0);
        atomicAdd(&ls1[g], di * a1);
        atomicAdd(&lc [g], 1.0f);
    }
    __syncthreads();

    #pragma unroll
    for (int g = tid; g < N_GRAPHS; g += 256) {
        float c = lc[g];
        if (c != 0.0f) {
            atomicAdd(&psum[g * 2 + 0], ls0[g]);
            atomicAdd(&psum[g * 2 + 1], ls1[g]);
            atomicAdd(&pcnt[g], c);
        }
    }
}

__global__ __launch_bounds__(256) void k_final(const float* __restrict__ psum,
                                               const float* __restrict__ pcnt,
                                               const float* __restrict__ b3,
                                               float* __restrict__ out) {
    int g = blockIdx.x * 256 + threadIdx.x;
    if (g >= N_GRAPHS) return;
    float c  = pcnt[g];
    float cc = fmaxf(c, 1.0f);
    out[g * 2 + 0] = (psum[g * 2 + 0] + c * b3[0]) / cc;
    out[g * 2 + 1] = (psum[g * 2 + 1] + c * b3[1]) / cc;
}

// ---------------------------------------------------------------------------
extern "C" void kernel_launch(void* const* d_in, const int* in_sizes, int n_in,
                              void* d_out, int out_size, void* d_ws, size_t ws_size,
                              hipStream_t stream) {
    const float* x     = (const float*)d_in[0];
    const int*   ei    = (const int*)d_in[1];
    const int*   batch = (const int*)d_in[2];
    const float* W1    = (const float*)d_in[3];
    const float* b1    = (const float*)d_in[4];
    const float* W2    = (const float*)d_in[5];
    const float* b2    = (const float*)d_in[6];
    const float* W3    = (const float*)d_in[7];
    const float* b3    = (const float*)d_in[8];
    const int* src = ei;
    const int* dst = ei + N_EDGES;

    float* ws   = (float*)d_ws;
    float* dinv = ws;                            // NPAD floats
    int*   degi = (int*)(dinv + NPAD);           // NPAD
    int*   offs = degi + NPAD;                   // NPAD
    int*   cnt  = offs + NPAD;                   // NPAD
    int*   bsum = cnt + NPAD;                    // 256
    int*   boff = bsum + 256;                    // 256
    int*   csr  = boff + 256;                    // N_EDGES
    float* xw   = (float*)(csr + N_EDGES);       // 3,200,000
    float* agg  = xw + (size_t)N_NODES * 64;     // 3,200,000
    float* psum = agg + (size_t)N_NODES * 64;    // 1024
    float* pcnt = psum + 1024;                   // 512
    float* out  = (float*)d_out;

    hipMemsetAsync(degi, 0, NPAD * sizeof(int), stream);
    hipMemsetAsync(cnt,  0, NPAD * sizeof(int), stream);
    hipMemsetAsync(psum, 0, (1024 + 512) * sizeof(float), stream);

    // ---- graph preprocessing: degrees, dinv, CSR
    k_degi<<<(N_EDGES + 255) / 256, 256, 0, stream>>>(dst, degi);
    k_dinv<<<(N_NODES + 255) / 256, 256, 0, stream>>>(degi, dinv);
    k_scan_block<<<NBLK, 256, 0, stream>>>(degi, offs, bsum);
    k_scan_bsum<<<1, 256, 0, stream>>>(bsum, boff);
    k_scan_add<<<NBLK, 256, 0, stream>>>(offs, boff);
    k_fill<<<(N_EDGES + 255) / 256, 256, 0, stream>>>(src, dst, offs, cnt, csr);

    // ---- layer 1: yw1 = dinv * (x @ W1); agg1 = dinv * (self + gather)
    k_gemm64t<128, false><<<(N_NODES + 63) / 64, 256, 0, stream>>>(x, W1, nullptr, dinv, xw);
    k_gather64<<<(N_NODES * 64) / 256, 256, 0, stream>>>(csr, offs, degi, dinv, xw, agg);

    // ---- layer 2
    k_gemm64t<64, true><<<(N_NODES + 63) / 64, 256, 0, stream>>>(agg, W2, b1, dinv, xw);
    k_gather64<<<(N_NODES * 64) / 256, 256, 0, stream>>>(csr, offs, degi, dinv, xw, agg);

    // ---- layer 3: yw3 = dinv * (relu(agg2+b2) @ W3); fused gather+pool
    k_gemm2<<<(N_NODES + 255) / 256, 256, 0, stream>>>(agg, W3, b2, dinv, xw);
    k_gather2pool<<<(N_NODES + 255) / 256, 256, 0, stream>>>(csr, offs, degi, dinv, xw,
                                                             batch, psum, pcnt);

    // ---- final
    k_final<<<(N_GRAPHS + 255) / 256, 256, 0, stream>>>(psum, pcnt, b3, out);
}

// Round 10
// 294.516 us; speedup vs baseline: 5.8628x; 1.0215x over previous
//
#include <hip/hip_runtime.h>
#include <hip/hip_bf16.h>

#define N_NODES   50000
#define N_EDGES   800000
#define N_GRAPHS  512
#define IN_DIM    128
#define HIDDEN    64
#define NPAD      50176          // 196 * 256, padded node count for scan
#define NBLK      196            // scan blocks
#define SHARD_BLOCKS 1024        // 128 blocks per shard x 8 shards

// ---------------------------------------------------------------------------
// XCD-sharded degree histogram: shard s owns nodes with ((d>>4)&7)==s, so
// every 64B line of degi is written from one shard (one XCD under %8 mapping).
__global__ __launch_bounds__(256) void k_degi_sh(const int* __restrict__ dst,
                                                 int* __restrict__ degi) {
    const int shard = blockIdx.x & 7;
    const int blk   = blockIdx.x >> 3;
    const int nthr  = (SHARD_BLOCKS >> 3) * 256;
    for (int e = blk * 256 + threadIdx.x; e < N_EDGES; e += nthr) {
        int d = dst[e];
        if (((d >> 4) & 7) == shard) atomicAdd(&degi[d], 1);
    }
}

__global__ __launch_bounds__(256) void k_dinv(const int* __restrict__ degi,
                                              float* __restrict__ dinv) {
    int i = blockIdx.x * 256 + threadIdx.x;
    if (i < N_NODES) dinv[i] = rsqrtf((float)degi[i] + 1.0f);
}

// ---------------------------------------------------------------------------
// two-level exclusive scan over degi[NPAD] -> offs
__global__ __launch_bounds__(256) void k_scan_block(const int* __restrict__ degi,
                                                    int* __restrict__ offs,
                                                    int* __restrict__ bsum) {
    __shared__ int sh[256];
    int tid = threadIdx.x;
    int i = blockIdx.x * 256 + tid;
    int v = degi[i];
    sh[tid] = v;
    __syncthreads();
    #pragma unroll
    for (int off = 1; off < 256; off <<= 1) {
        int t = (tid >= off) ? sh[tid - off] : 0;
        __syncthreads();
        sh[tid] += t;
        __syncthreads();
    }
    offs[i] = sh[tid] - v;                     // exclusive
    if (tid == 255) bsum[blockIdx.x] = sh[tid];
}

__global__ __launch_bounds__(256) void k_scan_bsum(int* __restrict__ bsum,
                                                   int* __restrict__ boff) {
    __shared__ int sh[256];
    int tid = threadIdx.x;
    int v = (tid < NBLK) ? bsum[tid] : 0;
    sh[tid] = v;
    __syncthreads();
    #pragma unroll
    for (int off = 1; off < 256; off <<= 1) {
        int t = (tid >= off) ? sh[tid - off] : 0;
        __syncthreads();
        sh[tid] += t;
        __syncthreads();
    }
    if (tid < NBLK) boff[tid] = sh[tid] - v;   // exclusive block offsets
}

// adds block offsets AND seeds cnt with the final offs value, so k_fill_sh's
// atomicAdd(&cnt[d],1) returns the CSR slot directly (no offs read per edge).
__global__ __launch_bounds__(256) void k_scan_add(int* __restrict__ offs,
                                                  const int* __restrict__ boff,
                                                  int* __restrict__ cnt) {
    int i = blockIdx.x * 256 + threadIdx.x;
    int v = offs[i] + boff[blockIdx.x];
    offs[i] = v;
    cnt[i]  = v;
}

// XCD-sharded CSR fill: csr_src[atomicAdd(&cnt[d],1)] = src(e), sharded by
// ((d>>4)&7) so each csr/cnt line is written from a single shard.
__global__ __launch_bounds__(256) void k_fill_sh(const int* __restrict__ src,
                                                 const int* __restrict__ dst,
                                                 int* __restrict__ cnt,
                                                 int* __restrict__ csr_src) {
    const int shard = blockIdx.x & 7;
    const int blk   = blockIdx.x >> 3;
    const int nthr  = (SHARD_BLOCKS >> 3) * 256;
    for (int e = blk * 256 + threadIdx.x; e < N_EDGES; e += nthr) {
        int d = dst[e];
        int s = src[e];
        if (((d >> 4) & 7) == shard) {
            int pos = atomicAdd(&cnt[d], 1);
            csr_src[pos] = s;
        }
    }
}

// ---------------------------------------------------------------------------
// Register-tiled GEMM: out[N][64] = dinv[row] * ( f(A)[N][K] @ W[K][64] )
// f = identity or relu(x + bin).  Block: 64 rows x 64 cols, 256 threads,
// each thread a 4x4 micro-tile.  K processed in 64-chunks.
template <int K, bool RELU_IN>
__global__ __launch_bounds__(256) void k_gemm64t(const float* __restrict__ A,
                                                 const float* __restrict__ W,
                                                 const float* __restrict__ bin,
                                                 const float* __restrict__ dinv,
                                                 float* __restrict__ out) {
    __shared__ float sA[64][65];   // [row][k], pad 65 -> conflict-free
    __shared__ float sW[64][64];   // [k][col] chunk
    __shared__ float sB[64];

    const int tid = threadIdx.x;
    const int rowBase = blockIdx.x * 64;
    const int c0 = (tid & 15) * 4;
    const int r0 = (tid >> 4) * 4;

    if (RELU_IN && tid < 64) sB[tid] = bin[tid];

    float acc[4][4];
    #pragma unroll
    for (int j = 0; j < 4; ++j)
        #pragma unroll
        for (int c = 0; c < 4; ++c) acc[j][c] = 0.0f;

    for (int kc = 0; kc < K; kc += 64) {
        __syncthreads();
        // stage W chunk: 64x64 floats = 1024 float4, 4 per thread
        #pragma unroll
        for (int p = 0; p < 4; ++p) {
            int i = p * 256 + tid;          // float4 id
            int k  = i >> 4;
            int cq = i & 15;
            *reinterpret_cast<float4*>(&sW[k][cq * 4]) =
                *reinterpret_cast<const float4*>(&W[(size_t)(kc + k) * 64 + cq * 4]);
        }
        // stage A chunk: 64 rows x 64 k = 1024 float4, 4 per thread
        #pragma unroll
        for (int p = 0; p < 4; ++p) {
            int i = p * 256 + tid;
            int row = i >> 4;
            int kq  = i & 15;
            int gr = rowBase + row;
            float4 v = make_float4(0.f, 0.f, 0.f, 0.f);
            if (gr < N_NODES)
                v = *reinterpret_cast<const float4*>(&A[(size_t)gr * K + kc + kq * 4]);
            if (RELU_IN) {
                v.x = fmaxf(v.x + sB[kq * 4 + 0], 0.f);
                v.y = fmaxf(v.y + sB[kq * 4 + 1], 0.f);
                v.z = fmaxf(v.z + sB[kq * 4 + 2], 0.f);
                v.w = fmaxf(v.w + sB[kq * 4 + 3], 0.f);
            }
            sA[row][kq * 4 + 0] = v.x;
            sA[row][kq * 4 + 1] = v.y;
            sA[row][kq * 4 + 2] = v.z;
            sA[row][kq * 4 + 3] = v.w;
        }
        __syncthreads();

        #pragma unroll 8
        for (int k = 0; k < 64; ++k) {
            float4 w4 = *reinterpret_cast<const float4*>(&sW[k][c0]);
            float a0 = sA[r0 + 0][k];
            float a1 = sA[r0 + 1][k];
            float a2 = sA[r0 + 2][k];
            float a3 = sA[r0 + 3][k];
            acc[0][0] = fmaf(a0, w4.x, acc[0][0]);
            acc[0][1] = fmaf(a0, w4.y, acc[0][1]);
            acc[0][2] = fmaf(a0, w4.z, acc[0][2]);
            acc[0][3] = fmaf(a0, w4.w, acc[0][3]);
            acc[1][0] = fmaf(a1, w4.x, acc[1][0]);
            acc[1][1] = fmaf(a1, w4.y, acc[1][1]);
            acc[1][2] = fmaf(a1, w4.z, acc[1][2]);
            acc[1][3] = fmaf(a1, w4.w, acc[1][3]);
            acc[2][0] = fmaf(a2, w4.x, acc[2][0]);
            acc[2][1] = fmaf(a2, w4.y, acc[2][1]);
            acc[2][2] = fmaf(a2, w4.z, acc[2][2]);
            acc[2][3] = fmaf(a2, w4.w, acc[2][3]);
            acc[3][0] = fmaf(a3, w4.x, acc[3][0]);
            acc[3][1] = fmaf(a3, w4.y, acc[3][1]);
            acc[3][2] = fmaf(a3, w4.z, acc[3][2]);
            acc[3][3] = fmaf(a3, w4.w, acc[3][3]);
        }
    }

    // epilogue: scale row by dinv, store float4
    #pragma unroll
    for (int j = 0; j < 4; ++j) {
        int gr = rowBase + r0 + j;
        if (gr < N_NODES) {
            float di = dinv[gr];
            float4 o;
            o.x = di * acc[j][0];
            o.y = di * acc[j][1];
            o.z = di * acc[j][2];
            o.w = di * acc[j][3];
            *reinterpret_cast<float4*>(&out[(size_t)gr * 64 + c0]) = o;
        }
    }
}

// out[N][2] = dinv[i] * ( relu(A + b2) @ W3[64][2] )
__global__ __launch_bounds__(256) void k_gemm2(const float* __restrict__ A,
                                               const float* __restrict__ W3,
                                               const float* __restrict__ b2,
                                               const float* __restrict__ dinv,
                                               float* __restrict__ out) {
    __shared__ float sW[128];
    __shared__ float sB[64];
    int tid = threadIdx.x;
    if (tid < 128) sW[tid] = W3[tid];
    if (tid < 64)  sB[tid] = b2[tid];
    __syncthreads();
    int i = blockIdx.x * 256 + tid;
    if (i >= N_NODES) return;
    float a0 = 0.f, a1 = 0.f;
    const float* row = A + (size_t)i * 64;
    #pragma unroll
    for (int k = 0; k < 64; k += 4) {
        float4 v = *reinterpret_cast<const float4*>(row + k);
        float z;
        z = fmaxf(v.x + sB[k + 0], 0.f); a0 = fmaf(z, sW[(k+0)*2+0], a0); a1 = fmaf(z, sW[(k+0)*2+1], a1);
        z = fmaxf(v.y + sB[k + 1], 0.f); a0 = fmaf(z, sW[(k+1)*2+0], a0); a1 = fmaf(z, sW[(k+1)*2+1], a1);
        z = fmaxf(v.z + sB[k + 2], 0.f); a0 = fmaf(z, sW[(k+2)*2+0], a0); a1 = fmaf(z, sW[(k+2)*2+1], a1);
        z = fmaxf(v.w + sB[k + 3], 0.f); a0 = fmaf(z, sW[(k+3)*2+0], a0); a1 = fmaf(z, sW[(k+3)*2+1], a1);
    }
    float di = dinv[i];
    out[i * 2 + 0] = di * a0;
    out[i * 2 + 1] = di * a1;
}

// ---------------------------------------------------------------------------
// gather aggregation D=64: one wave per node, lane = feature dim.
// yw is pre-scaled by dinv[src]; out = dinv[node] * (yw[node] + sum yw[s]).
__global__ __launch_bounds__(256) void k_gather64(const int* __restrict__ csr_src,
                                                  const int* __restrict__ offs,
                                                  const int* __restrict__ degi,
                                                  const float* __restrict__ dinv,
                                                  const float* __restrict__ yw,
                                                  float* __restrict__ agg) {
    int gid  = blockIdx.x * 256 + threadIdx.x;
    int node = gid >> 6;
    int lane = threadIdx.x & 63;
    if (node >= N_NODES) return;
    float acc = yw[(size_t)node * 64 + lane];   // self-loop term (pre-scaled)
    int beg = offs[node];
    int n   = degi[node];
    int j = 0;
    for (; j + 7 < n; j += 8) {
        int s[8];
        #pragma unroll
        for (int u = 0; u < 8; ++u) s[u] = csr_src[beg + j + u];
        float v[8];
        #pragma unroll
        for (int u = 0; u < 8; ++u) v[u] = yw[(size_t)s[u] * 64 + lane];
        #pragma unroll
        for (int u = 0; u < 8; ++u) acc += v[u];
    }
    for (; j < n; ++j) {
        int s = csr_src[beg + j];
        acc += yw[(size_t)s * 64 + lane];
    }
    agg[(size_t)node * 64 + lane] = dinv[node] * acc;
}

// ---------------------------------------------------------------------------
// Fused layer-3 gather + pooling.  Blocks cover 256 consecutive nodes; batch
// is sorted, so a block spans only a handful of graph ids.  Per-node result
// goes into LDS per-graph bins (LDS atomics), then one global atomic per
// (block, graph).
__global__ __launch_bounds__(256) void k_gather2pool(const int* __restrict__ csr_src,
                                                     const int* __restrict__ offs,
                                                     const int* __restrict__ degi,
                                                     const float* __restrict__ dinv,
                                                     const float* __restrict__ yw,
                                                     const int* __restrict__ batch,
                                                     float* __restrict__ psum,
                                                     float* __restrict__ pcnt) {
    __shared__ float ls0[N_GRAPHS];
    __shared__ float ls1[N_GRAPHS];
    __shared__ float lc [N_GRAPHS];
    int tid = threadIdx.x;
    #pragma unroll
    for (int g = tid; g < N_GRAPHS; g += 256) {
        ls0[g] = 0.f; ls1[g] = 0.f; lc[g] = 0.f;
    }
    __syncthreads();

    int node = blockIdx.x * 256 + tid;
    if (node < N_NODES) {
        float2 v = *reinterpret_cast<const float2*>(&yw[(size_t)node * 2]);
        float a0 = v.x, a1 = v.y;
        int beg = offs[node];
        int n   = degi[node];
        for (int j = 0; j < n; ++j) {
            int s = csr_src[beg + j];
            float2 u = *reinterpret_cast<const float2*>(&yw[(size_t)s * 2]);
            a0 += u.x;
            a1 += u.y;
        }
        float di = dinv[node];
        int g = batch[node];
        atomicAdd(&ls0[g], di * a0);
        atomicAdd(&ls1[g], di * a1);
        atomicAdd(&lc [g], 1.0f);
    }
    __syncthreads();

    #pragma unroll
    for (int g = tid; g < N_GRAPHS; g += 256) {
        float c = lc[g];
        if (c != 0.0f) {
            atomicAdd(&psum[g * 2 + 0], ls0[g]);
            atomicAdd(&psum[g * 2 + 1], ls1[g]);
            atomicAdd(&pcnt[g], c);
        }
    }
}

__global__ __launch_bounds__(256) void k_final(const float* __restrict__ psum,
                                               const float* __restrict__ pcnt,
                                               const float* __restrict__ b3,
                                               float* __restrict__ out) {
    int g = blockIdx.x * 256 + threadIdx.x;
    if (g >= N_GRAPHS) return;
    float c  = pcnt[g];
    float cc = fmaxf(c, 1.0f);
    out[g * 2 + 0] = (psum[g * 2 + 0] + c * b3[0]) / cc;
    out[g * 2 + 1] = (psum[g * 2 + 1] + c * b3[1]) / cc;
}

// ---------------------------------------------------------------------------
extern "C" void kernel_launch(void* const* d_in, const int* in_sizes, int n_in,
                              void* d_out, int out_size, void* d_ws, size_t ws_size,
                              hipStream_t stream) {
    const float* x     = (const float*)d_in[0];
    const int*   ei    = (const int*)d_in[1];
    const int*   batch = (const int*)d_in[2];
    const float* W1    = (const float*)d_in[3];
    const float* b1    = (const float*)d_in[4];
    const float* W2    = (const float*)d_in[5];
    const float* b2    = (const float*)d_in[6];
    const float* W3    = (const float*)d_in[7];
    const float* b3    = (const float*)d_in[8];
    const int* src = ei;
    const int* dst = ei + N_EDGES;

    float* ws   = (float*)d_ws;
    float* dinv = ws;                            // NPAD floats
    int*   degi = (int*)(dinv + NPAD);           // NPAD
    int*   offs = degi + NPAD;                   // NPAD
    int*   cnt  = offs + NPAD;                   // NPAD
    int*   bsum = cnt + NPAD;                    // 256
    int*   boff = bsum + 256;                    // 256
    int*   csr  = boff + 256;                    // N_EDGES
    float* xw   = (float*)(csr + N_EDGES);       // 3,200,000
    float* agg  = xw + (size_t)N_NODES * 64;     // 3,200,000
    float* psum = agg + (size_t)N_NODES * 64;    // 1024
    float* pcnt = psum + 1024;                   // 512
    float* out  = (float*)d_out;

    hipMemsetAsync(degi, 0, NPAD * sizeof(int), stream);
    hipMemsetAsync(psum, 0, (1024 + 512) * sizeof(float), stream);

    // ---- graph preprocessing: degrees, dinv, CSR (XCD-sharded)
    k_degi_sh<<<SHARD_BLOCKS, 256, 0, stream>>>(dst, degi);
    k_dinv<<<(N_NODES + 255) / 256, 256, 0, stream>>>(degi, dinv);
    k_scan_block<<<NBLK, 256, 0, stream>>>(degi, offs, bsum);
    k_scan_bsum<<<1, 256, 0, stream>>>(bsum, boff);
    k_scan_add<<<NBLK, 256, 0, stream>>>(offs, boff, cnt);
    k_fill_sh<<<SHARD_BLOCKS, 256, 0, stream>>>(src, dst, cnt, csr);

    // ---- layer 1: yw1 = dinv * (x @ W1); agg1 = dinv * (self + gather)
    k_gemm64t<128, false><<<(N_NODES + 63) / 64, 256, 0, stream>>>(x, W1, nullptr, dinv, xw);
    k_gather64<<<(N_NODES * 64) / 256, 256, 0, stream>>>(csr, offs, degi, dinv, xw, agg);

    // ---- layer 2
    k_gemm64t<64, true><<<(N_NODES + 63) / 64, 256, 0, stream>>>(agg, W2, b1, dinv, xw);
    k_gather64<<<(N_NODES * 64) / 256, 256, 0, stream>>>(csr, offs, degi, dinv, xw, agg);

    // ---- layer 3: yw3 = dinv * (relu(agg2+b2) @ W3); fused gather+pool
    k_gemm2<<<(N_NODES + 255) / 256, 256, 0, stream>>>(agg, W3, b2, dinv, xw);
    k_gather2pool<<<(N_NODES + 255) / 256, 256, 0, stream>>>(csr, offs, degi, dinv, xw,
                                                             batch, psum, pcnt);

    // ---- final
    k_final<<<(N_GRAPHS + 255) / 256, 256, 0, stream>>>(psum, pcnt, b3, out);
}